// Round 8
// baseline (1918.515 us; speedup 1.0000x reference)
//
#include <hip/hip_runtime.h>

#define CHANNELS 32
#define HIDDEN 1024
#define LAYERS 8
#define NRANGE 8

typedef __attribute__((ext_vector_type(8))) short short8;
typedef __attribute__((ext_vector_type(4))) float float4v;

__device__ __forceinline__ short f2bf_rne(float f) {
    union { float f; unsigned u; } v; v.f = f;
    unsigned r = v.u + 0x7fffu + ((v.u >> 16) & 1u);
    return (short)(r >> 16);
}
__device__ __forceinline__ float bf2f(short h) {
    union { float f; unsigned u; } v; v.u = ((unsigned)(unsigned short)h) << 16;
    return v.f;
}
__device__ __forceinline__ float bfu2f(unsigned short h) {
    union { float f; unsigned u; } v; v.u = ((unsigned)h) << 16;
    return v.f;
}

// ---------------- degree count, range-split (XCD-affine), nt edge reads -------

__global__ __launch_bounds__(256)
void deg_range_kernel(const int* __restrict__ src, const int* __restrict__ tgt,
                      int* __restrict__ deg2, int n_nodes, int n_edges, int rsh) {
    int r = blockIdx.x & (NRANGE - 1);
    int chunk = blockIdx.x >> 3;
    int base = chunk * 2048;
#pragma unroll
    for (int j = 0; j < 8; j++) {
        int e = base + j * 256 + threadIdx.x;
        if (e < n_edges) {
            int t = __builtin_nontemporal_load(tgt + e);
            int s = __builtin_nontemporal_load(src + e);
            if ((t >> rsh) == r) atomicAdd(&deg2[t], 1);
            if ((s >> rsh) == r) atomicAdd(&deg2[n_nodes + s], 1);
        }
    }
}

// ---------------- 3-kernel exclusive prefix scan over deg2[0..n2) ----------------

__global__ __launch_bounds__(256)
void scan_pass1(const int* __restrict__ deg, int* __restrict__ bs, int n) {
    __shared__ int sh[256];
    int t = threadIdx.x;
    int base = blockIdx.x * 2048 + t * 8;
    int s = 0;
#pragma unroll
    for (int j = 0; j < 8; j++) { int idx = base + j; if (idx < n) s += deg[idx]; }
    sh[t] = s; __syncthreads();
    for (int st = 128; st > 0; st >>= 1) { if (t < st) sh[t] += sh[t + st]; __syncthreads(); }
    if (t == 0) bs[blockIdx.x] = sh[0];
}

__global__ void scan_pass2(int* __restrict__ bs, int nb) {
    __shared__ int sh[1024];
    int t = threadIdx.x;
    int v = (t < nb) ? bs[t] : 0;
    sh[t] = v; __syncthreads();
    for (int off = 1; off < 1024; off <<= 1) {
        int u = (t >= off) ? sh[t - off] : 0; __syncthreads();
        sh[t] += u; __syncthreads();
    }
    if (t < nb) bs[t] = sh[t] - v;   // exclusive
}

__global__ __launch_bounds__(256)
void scan_pass3(const int* __restrict__ deg, const int* __restrict__ bs,
                int* __restrict__ off, int n) {
    __shared__ int sh[256];
    int t = threadIdx.x;
    int base = blockIdx.x * 2048 + t * 8;
    int v[8]; int s = 0;
#pragma unroll
    for (int j = 0; j < 8; j++) { int idx = base + j; v[j] = (idx < n) ? deg[idx] : 0; s += v[j]; }
    sh[t] = s; __syncthreads();
    for (int st = 1; st < 256; st <<= 1) {
        int u = (t >= st) ? sh[t - st] : 0; __syncthreads();
        sh[t] += u; __syncthreads();
    }
    int acc = bs[blockIdx.x] + sh[t] - s;
#pragma unroll
    for (int j = 0; j < 8; j++) { int idx = base + j; if (idx < n) off[idx] = acc; acc += v[j]; }
}

// ---------------- scatter edges, 16 ranges over 2 launches, nt edge reads -----

__global__ __launch_bounds__(256)
void scatter_range_kernel(const int* __restrict__ src, const int* __restrict__ tgt,
                          int* __restrict__ cur2, int* __restrict__ nbr,
                          int n_nodes, int n_edges, int rsh, int rbase) {
    int r = rbase + (blockIdx.x & (NRANGE - 1));
    int chunk = blockIdx.x >> 3;
    int base = chunk * 2048;
#pragma unroll
    for (int j = 0; j < 8; j++) {
        int e = base + j * 256 + threadIdx.x;
        if (e < n_edges) {
            int t = __builtin_nontemporal_load(tgt + e);
            int s = __builtin_nontemporal_load(src + e);
            if ((t >> rsh) == r) { int p = atomicAdd(&cur2[t], 1);           nbr[p] = s; }
            if ((s >> rsh) == r) { int q = atomicAdd(&cur2[n_nodes + s], 1); nbr[q] = t; }
        }
    }
}

// ---------------- init: x (fp32) + xg (bf16 mirror), norms ----------------

__global__ __launch_bounds__(256)
void init_kernel(const int* __restrict__ nodes, const float* __restrict__ emb,
                 const int* __restrict__ deg2,
                 float* __restrict__ x, unsigned short* __restrict__ xg,
                 float* __restrict__ norm, float* __restrict__ norm_t, int n_nodes) {
    int gid = blockIdx.x * blockDim.x + threadIdx.x;
    int i = gid >> 5, c = gid & 31;
    if (i >= n_nodes) return;
    float v = emb[nodes[i] * CHANNELS + c];
    x[gid] = v;
    xg[gid] = (unsigned short)f2bf_rne(v);
    if (c == 0) {
        norm[i]   = 1.0f / (1.0f + (float)deg2[i]);
        norm_t[i] = 1.0f / (1.0f + (float)deg2[n_nodes + i]);
    }
}

// ---------------- counts via binary search over sorted batch ----------------

__global__ void counts_kernel(const int* __restrict__ batch, float* __restrict__ counts,
                              int n_nodes, int n_graphs) {
    int b = blockIdx.x * blockDim.x + threadIdx.x;
    if (b >= n_graphs) return;
    int lo = 0, hi = n_nodes;
    while (lo < hi) { int mid = (lo + hi) >> 1; if (batch[mid] < b) lo = mid + 1; else hi = mid; }
    int s = lo;
    lo = 0; hi = n_nodes;
    while (lo < hi) { int mid = (lo + hi) >> 1; if (batch[mid] < b + 1) lo = mid + 1; else hi = mid; }
    counts[b] = (float)(lo - s);
}

// ---------------- fused layer: node-parallel, 2 nodes/group/iter + MFMA -------
// Block = 64 nodes, 256 threads = 8 groups x 32 channels. Group g owns locals
// [8g, 8g+8); each iteration processes TWO nodes (16 row-gathers in flight)
// and prefetches the next pair's nbr-index rows + x rows. CSR offsets in LDS.

__device__ __forceinline__ void load_node_state(
    const int* __restrict__ nbr, const float* __restrict__ x,
    const int* offIn, const int* offOut,
    int nodeblock, int local, int c, int n_nodes,
    int& node, int& bi, int& d1, int& bo, int& d2,
    int& nb1, int& nb2, float& xv)
{
    node = nodeblock + local;
    bi = offIn[local];  d1 = offIn[local + 1] - bi;
    bo = offOut[local]; d2 = offOut[local + 1] - bo;
    nb1 = (c < d1) ? nbr[bi + c] : 0;
    nb2 = (c < d2) ? nbr[bo + c] : 0;
    xv = (node < n_nodes) ? x[node * CHANNELS + c] : 0.f;
}

__global__ __launch_bounds__(256)
void layer_mfma(const int* __restrict__ off2, const int* __restrict__ nbr,
                const float* __restrict__ wbase,
                const float* __restrict__ norm, const float* __restrict__ norm_t,
                float* __restrict__ x,
                const unsigned short* __restrict__ xgin,
                unsigned short* __restrict__ xgout,
                int n_nodes, int n_edges) {
    __shared__ short A1h[64][32], A1l[64][32], A2h[64][32], A2l[64][32];
    __shared__ short W0h[32][32], W0l[32][32], W1h[32][32], W1l[32][32]; // [n][k]
    __shared__ int offIn[65], offOut[65];

    int tid = threadIdx.x;
    int nodeblock = blockIdx.x * 64;

    for (int idx = tid; idx < CHANNELS * CHANNELS; idx += 256) {
        int k = idx >> 5, n = idx & 31;
        float w0 = wbase[idx];
        float w1 = wbase[CHANNELS * CHANNELS + idx];
        short h0 = f2bf_rne(w0); W0h[n][k] = h0; W0l[n][k] = f2bf_rne(w0 - bf2f(h0));
        short h1 = f2bf_rne(w1); W1h[n][k] = h1; W1l[n][k] = f2bf_rne(w1 - bf2f(h1));
    }
    if (tid < 65) {
        int idx = nodeblock + tid;
        offIn[tid]  = (idx <= n_nodes) ? off2[idx] : n_edges;
        int idx2 = n_nodes + idx;
        offOut[tid] = (idx2 < 2 * n_nodes) ? off2[idx2] : 2 * n_edges;
    }
    __syncthreads();

    int c = tid & 31, g = tid >> 5;
    int baseL = g * 8;

    int nodeA, biA, d1A, boA, d2A, nbA1, nbA2; float xvA;
    int nodeB, biB, d1B, boB, d2B, nbB1, nbB2; float xvB;
    load_node_state(nbr, x, offIn, offOut, nodeblock, baseL,     c, n_nodes,
                    nodeA, biA, d1A, boA, d2A, nbA1, nbA2, xvA);
    load_node_state(nbr, x, offIn, offOut, nodeblock, baseL + 1, c, n_nodes,
                    nodeB, biB, d1B, boB, d2B, nbB1, nbB2, xvB);

    for (int it = 0; it < 4; it++) {
        // prefetch next pair (issues loads that land during this pair's gathers)
        int nodeA_n = 0, biA_n = 0, d1A_n = 0, boA_n = 0, d2A_n = 0, nbA1_n = 0, nbA2_n = 0;
        int nodeB_n = 0, biB_n = 0, d1B_n = 0, boB_n = 0, d2B_n = 0, nbB1_n = 0, nbB2_n = 0;
        float xvA_n = 0.f, xvB_n = 0.f;
        if (it < 3) {
            load_node_state(nbr, x, offIn, offOut, nodeblock, baseL + 2 * it + 2, c, n_nodes,
                            nodeA_n, biA_n, d1A_n, boA_n, d2A_n, nbA1_n, nbA2_n, xvA_n);
            load_node_state(nbr, x, offIn, offOut, nodeblock, baseL + 2 * it + 3, c, n_nodes,
                            nodeB_n, biB_n, d1B_n, boB_n, d2B_n, nbB1_n, nbB2_n, xvB_n);
        }

        int selfA = (nodeA < n_nodes) ? nodeA : 0;
        int selfB = (nodeB < n_nodes) ? nodeB : 0;
        int m1A = d1A < 32 ? d1A : 32;
        int m2A = d2A < 32 ? d2A : 32;
        int m1B = d1B < 32 ? d1B : 32;
        int m2B = d2B < 32 ? d2B : 32;
        int mm = m1A > m2A ? m1A : m2A;
        int mb = m1B > m2B ? m1B : m2B;
        mm = mm > mb ? mm : mb;

        float a1A = 0.f, a2A = 0.f, a1B = 0.f, a2B = 0.f;
        for (int j = 0; j < mm; j += 4) {
            int pA[4], qA[4], pB[4], qB[4];
#pragma unroll
            for (int u = 0; u < 4; u++) {
                int jj = (j + u) & 31;
                pA[u] = __shfl(nbA1, jj, 32);
                qA[u] = __shfl(nbA2, jj, 32);
                pB[u] = __shfl(nbB1, jj, 32);
                qB[u] = __shfl(nbB2, jj, 32);
                pA[u] = (j + u < m1A) ? pA[u] : selfA;
                qA[u] = (j + u < m2A) ? qA[u] : selfA;
                pB[u] = (j + u < m1B) ? pB[u] : selfB;
                qB[u] = (j + u < m2B) ? qB[u] : selfB;
            }
            float vA1[4], vA2[4], vB1[4], vB2[4];
#pragma unroll
            for (int u = 0; u < 4; u++) {
                vA1[u] = bfu2f(xgin[pA[u] * CHANNELS + c]);
                vA2[u] = bfu2f(xgin[qA[u] * CHANNELS + c]);
                vB1[u] = bfu2f(xgin[pB[u] * CHANNELS + c]);
                vB2[u] = bfu2f(xgin[qB[u] * CHANNELS + c]);
            }
#pragma unroll
            for (int u = 0; u < 4; u++) {
                a1A += (j + u < m1A) ? vA1[u] : 0.f;
                a2A += (j + u < m2A) ? vA2[u] : 0.f;
                a1B += (j + u < m1B) ? vB1[u] : 0.f;
                a2B += (j + u < m2B) ? vB2[u] : 0.f;
            }
        }
        // rare tails (degree > 32)
        for (int e = biA + 32; e < biA + d1A; e++) a1A += bfu2f(xgin[nbr[e] * CHANNELS + c]);
        for (int e = boA + 32; e < boA + d2A; e++) a2A += bfu2f(xgin[nbr[e] * CHANNELS + c]);
        for (int e = biB + 32; e < biB + d1B; e++) a1B += bfu2f(xgin[nbr[e] * CHANNELS + c]);
        for (int e = boB + 32; e < boB + d2B; e++) a2B += bfu2f(xgin[nbr[e] * CHANNELS + c]);

        int localA = baseL + 2 * it, localB = localA + 1;
        if (nodeA < n_nodes) {
            float a1 = norm[nodeA] * (xvA + a1A);
            float a2 = norm_t[nodeA] * (xvA + a2A);
            short h1 = f2bf_rne(a1);
            A1h[localA][c] = h1; A1l[localA][c] = f2bf_rne(a1 - bf2f(h1));
            short h2 = f2bf_rne(a2);
            A2h[localA][c] = h2; A2l[localA][c] = f2bf_rne(a2 - bf2f(h2));
        } else {
            A1h[localA][c] = 0; A1l[localA][c] = 0;
            A2h[localA][c] = 0; A2l[localA][c] = 0;
        }
        if (nodeB < n_nodes) {
            float a1 = norm[nodeB] * (xvB + a1B);
            float a2 = norm_t[nodeB] * (xvB + a2B);
            short h1 = f2bf_rne(a1);
            A1h[localB][c] = h1; A1l[localB][c] = f2bf_rne(a1 - bf2f(h1));
            short h2 = f2bf_rne(a2);
            A2h[localB][c] = h2; A2l[localB][c] = f2bf_rne(a2 - bf2f(h2));
        } else {
            A1h[localB][c] = 0; A1l[localB][c] = 0;
            A2h[localB][c] = 0; A2l[localB][c] = 0;
        }

        nodeA = nodeA_n; biA = biA_n; d1A = d1A_n; boA = boA_n; d2A = d2A_n;
        nbA1 = nbA1_n; nbA2 = nbA2_n; xvA = xvA_n;
        nodeB = nodeB_n; biB = biB_n; d1B = d1B_n; boB = boB_n; d2B = d2B_n;
        nbB1 = nbB1_n; nbB2 = nbB2_n; xvB = xvB_n;
    }
    __syncthreads();

    // ----- MFMA + epilogue -----
    int wv = tid >> 6, lane = tid & 63;
    int m = lane & 15, quad = lane >> 4;
    int row0 = wv * 16;

    short8 a1h = *(const short8*)&A1h[row0 + m][quad * 8];
    short8 a1l = *(const short8*)&A1l[row0 + m][quad * 8];
    short8 a2h = *(const short8*)&A2h[row0 + m][quad * 8];
    short8 a2l = *(const short8*)&A2l[row0 + m][quad * 8];

    float4v dd[4];
#pragma unroll
    for (int h = 0; h < 2; h++) {
        int n0 = h * 16 + m;
        short8 b0h = *(const short8*)&W0h[n0][quad * 8];
        short8 b0l = *(const short8*)&W0l[n0][quad * 8];
        short8 b1h = *(const short8*)&W1h[n0][quad * 8];
        short8 b1l = *(const short8*)&W1l[n0][quad * 8];
        float4v d1 = {0.f, 0.f, 0.f, 0.f};
        d1 = __builtin_amdgcn_mfma_f32_16x16x32_bf16(a1h, b0h, d1, 0, 0, 0);
        d1 = __builtin_amdgcn_mfma_f32_16x16x32_bf16(a1l, b0h, d1, 0, 0, 0);
        d1 = __builtin_amdgcn_mfma_f32_16x16x32_bf16(a1h, b0l, d1, 0, 0, 0);
        float4v d2 = {0.f, 0.f, 0.f, 0.f};
        d2 = __builtin_amdgcn_mfma_f32_16x16x32_bf16(a2h, b1h, d2, 0, 0, 0);
        d2 = __builtin_amdgcn_mfma_f32_16x16x32_bf16(a2l, b1h, d2, 0, 0, 0);
        d2 = __builtin_amdgcn_mfma_f32_16x16x32_bf16(a2h, b1l, d2, 0, 0, 0);
        dd[h * 2] = d1; dd[h * 2 + 1] = d2;
    }

#pragma unroll
    for (int h = 0; h < 2; h++) {
        float4v d1 = dd[h * 2], d2 = dd[h * 2 + 1];
#pragma unroll
        for (int r = 0; r < 4; r++) {
            int local = row0 + quad * 4 + r;
            int node = nodeblock + local;
            if (node < n_nodes) {
                int col = h * 16 + m;
                float v = x[node * CHANNELS + col] + fmaxf(d1[r], 0.f) + fmaxf(d2[r], 0.f);
                x[node * CHANNELS + col] = v;
                xgout[node * CHANNELS + col] = (unsigned short)f2bf_rne(v);
            }
        }
    }
}

// ---------------- pooling: run-length accumulate over sorted batch ----------------

#define POOL_CHUNK 2048

__global__ __launch_bounds__(256)
void pool_kernel(const int* __restrict__ batch, const float* __restrict__ x,
                 float* __restrict__ g, int n_nodes) {
    int c = threadIdx.x & 31;
    int r = threadIdx.x >> 5;
    int base = blockIdx.x * POOL_CHUNK;
    float acc = 0.f;
    int cur = -1;
    for (int it = 0; it < POOL_CHUNK / 8; it++) {
        int node = base + it * 8 + r;
        if (node >= n_nodes) break;
        int b = batch[node];
        if (b != cur) {
            if (cur >= 0) atomicAdd(&g[cur * CHANNELS + c], acc);
            acc = 0.f;
            cur = b;
        }
        acc += x[node * CHANNELS + c];
    }
    if (cur >= 0) atomicAdd(&g[cur * CHANNELS + c], acc);
}

// ---------------- MLP head: one block per graph ----------------

__global__ __launch_bounds__(256)
void mlp_kernel(const float* __restrict__ g, const float* __restrict__ counts,
                const float* __restrict__ hidden_w, const float* __restrict__ hidden_b,
                const float* __restrict__ out_w, float* __restrict__ out) {
    __shared__ float grow[CHANNELS];
    __shared__ float red[256];
    int graph = blockIdx.x;
    int tid = threadIdx.x;
    if (tid < CHANNELS) grow[tid] = g[graph * CHANNELS + tid] / counts[graph];
    __syncthreads();
    float partial = 0.f;
    for (int q = 0; q < HIDDEN / 256; q++) {
        int j = q * 256 + tid;
        float h = hidden_b[j];
#pragma unroll
        for (int k = 0; k < CHANNELS; k++) h += grow[k] * hidden_w[k * HIDDEN + j];
        partial += fmaxf(h, 0.f) * out_w[j];
    }
    red[tid] = partial;
    __syncthreads();
    for (int s = 128; s > 0; s >>= 1) {
        if (tid < s) red[tid] += red[tid + s];
        __syncthreads();
    }
    if (tid == 0) out[graph] = red[0];
}

// ---------------- launch ----------------

extern "C" void kernel_launch(void* const* d_in, const int* in_sizes, int n_in,
                              void* d_out, int out_size, void* d_ws, size_t ws_size,
                              hipStream_t stream) {
    const int*   nodes    = (const int*)d_in[0];
    const int*   sources  = (const int*)d_in[1];
    const int*   targets  = (const int*)d_in[2];
    const int*   batch    = (const int*)d_in[3];
    const float* emb      = (const float*)d_in[4];
    const float* conv_w   = (const float*)d_in[5];
    const float* hidden_w = (const float*)d_in[6];
    const float* hidden_b = (const float*)d_in[7];
    const float* out_w    = (const float*)d_in[8];
    float* out = (float*)d_out;

    const int n_nodes  = in_sizes[0];
    const int n_edges  = in_sizes[1];
    const int n_graphs = out_size;
    const int n2 = 2 * n_nodes;

    int rsh8 = 0;
    while (((n_nodes - 1) >> rsh8) >= 8) rsh8++;
    int rsh16 = 0;
    while (((n_nodes - 1) >> rsh16) >= 16) rsh16++;

    char* ws = (char*)d_ws;
    float*          x      = (float*)ws;          ws += (size_t)n_nodes * CHANNELS * 4;
    unsigned short* xg0    = (unsigned short*)ws; ws += (size_t)n_nodes * CHANNELS * 2;
    unsigned short* xg1    = (unsigned short*)ws; ws += (size_t)n_nodes * CHANNELS * 2;
    float* norm   = (float*)ws; ws += (size_t)n_nodes * 4;
    float* norm_t = (float*)ws; ws += (size_t)n_nodes * 4;
    int*   deg2   = (int*)ws;   ws += (size_t)n2 * 4;
    int*   off2   = (int*)ws;   ws += (size_t)n2 * 4;
    int*   cur2   = (int*)ws;   ws += (size_t)n2 * 4;
    int*   nbr    = (int*)ws;   ws += (size_t)2 * n_edges * 4;
    int*   bsums  = (int*)ws;   ws += 4096;
    float* g      = (float*)ws; ws += (size_t)n_graphs * CHANNELS * 4;
    float* counts = (float*)ws; ws += (size_t)n_graphs * 4;

    hipMemsetAsync(deg2, 0, (size_t)n2 * 4, stream);
    hipMemsetAsync(g, 0, (size_t)n_graphs * CHANNELS * 4, stream);

    int echunks = (n_edges + 2047) / 2048;

    // 1. degrees (8 ranges, XCD-affine, nt edge reads)
    deg_range_kernel<<<echunks * NRANGE, 256, 0, stream>>>(sources, targets, deg2,
                                                           n_nodes, n_edges, rsh8);

    // 2. exclusive scan deg2 -> off2
    int nblk = (n2 + 2047) / 2048;
    scan_pass1<<<nblk, 256, 0, stream>>>(deg2, bsums, n2);
    scan_pass2<<<1, 1024, 0, stream>>>(bsums, nblk);
    scan_pass3<<<nblk, 256, 0, stream>>>(deg2, bsums, off2, n2);

    // 3. cursors = offsets copy, then scatter (16 ranges over 2 launches)
    hipMemcpyAsync(cur2, off2, (size_t)n2 * 4, hipMemcpyDeviceToDevice, stream);
    scatter_range_kernel<<<echunks * NRANGE, 256, 0, stream>>>(sources, targets, cur2, nbr,
                                                               n_nodes, n_edges, rsh16, 0);
    scatter_range_kernel<<<echunks * NRANGE, 256, 0, stream>>>(sources, targets, cur2, nbr,
                                                               n_nodes, n_edges, rsh16, 8);

    // 4. init features + norms; counts via binary search
    int node_thr = n_nodes * CHANNELS;
    init_kernel<<<(node_thr + 255) / 256, 256, 0, stream>>>(nodes, emb, deg2, x, xg0,
                                                            norm, norm_t, n_nodes);
    counts_kernel<<<(n_graphs + 255) / 256, 256, 0, stream>>>(batch, counts, n_nodes, n_graphs);

    // 5. layers: fp32 x in place, bf16 mirror ping-pongs
    unsigned short* xgin = xg0; unsigned short* xgout = xg1;
    int lblocks = (n_nodes + 63) / 64;
    for (int l = 0; l < LAYERS; l++) {
        const float* wbase = conv_w + (size_t)l * 2 * CHANNELS * CHANNELS;
        layer_mfma<<<lblocks, 256, 0, stream>>>(off2, nbr, wbase, norm, norm_t,
                                                x, xgin, xgout, n_nodes, n_edges);
        unsigned short* tmp = xgin; xgin = xgout; xgout = tmp;
    }

    // 6. pool + head
    int pool_blocks = (n_nodes + POOL_CHUNK - 1) / POOL_CHUNK;
    pool_kernel<<<pool_blocks, 256, 0, stream>>>(batch, x, g, n_nodes);
    mlp_kernel<<<n_graphs, 256, 0, stream>>>(g, counts, hidden_w, hidden_b, out_w, out);
}

// Round 10
// 1823.427 us; speedup vs baseline: 1.0521x; 1.0521x over previous
//
#include <hip/hip_runtime.h>

#define CHANNELS 32
#define HIDDEN 1024
#define LAYERS 8
#define NRANGE 8
#define APAD 40   // tile row stride in shorts (80 B): breaks 64B-stride bank aliasing

typedef __attribute__((ext_vector_type(8))) short short8;
typedef __attribute__((ext_vector_type(4))) float float4v;

__device__ __forceinline__ short f2bf_rne(float f) {
    union { float f; unsigned u; } v; v.f = f;
    unsigned r = v.u + 0x7fffu + ((v.u >> 16) & 1u);
    return (short)(r >> 16);
}
__device__ __forceinline__ float bf2f(short h) {
    union { float f; unsigned u; } v; v.u = ((unsigned)(unsigned short)h) << 16;
    return v.f;
}
__device__ __forceinline__ float bfu2f(unsigned short h) {
    union { float f; unsigned u; } v; v.u = ((unsigned)h) << 16;
    return v.f;
}

// ---------------- degree count, range-split (XCD-affine), nt edge reads -------

__global__ __launch_bounds__(256)
void deg_range_kernel(const int* __restrict__ src, const int* __restrict__ tgt,
                      int* __restrict__ deg2, int n_nodes, int n_edges, int rsh) {
    int r = blockIdx.x & (NRANGE - 1);
    int chunk = blockIdx.x >> 3;
    int base = chunk * 2048;
#pragma unroll
    for (int j = 0; j < 8; j++) {
        int e = base + j * 256 + threadIdx.x;
        if (e < n_edges) {
            int t = __builtin_nontemporal_load(tgt + e);
            int s = __builtin_nontemporal_load(src + e);
            if ((t >> rsh) == r) atomicAdd(&deg2[t], 1);
            if ((s >> rsh) == r) atomicAdd(&deg2[n_nodes + s], 1);
        }
    }
}

// ---------------- 3-kernel exclusive prefix scan over deg2[0..n2) ----------------

__global__ __launch_bounds__(256)
void scan_pass1(const int* __restrict__ deg, int* __restrict__ bs, int n) {
    __shared__ int sh[256];
    int t = threadIdx.x;
    int base = blockIdx.x * 2048 + t * 8;
    int s = 0;
#pragma unroll
    for (int j = 0; j < 8; j++) { int idx = base + j; if (idx < n) s += deg[idx]; }
    sh[t] = s; __syncthreads();
    for (int st = 128; st > 0; st >>= 1) { if (t < st) sh[t] += sh[t + st]; __syncthreads(); }
    if (t == 0) bs[blockIdx.x] = sh[0];
}

__global__ void scan_pass2(int* __restrict__ bs, int nb) {
    __shared__ int sh[1024];
    int t = threadIdx.x;
    int v = (t < nb) ? bs[t] : 0;
    sh[t] = v; __syncthreads();
    for (int off = 1; off < 1024; off <<= 1) {
        int u = (t >= off) ? sh[t - off] : 0; __syncthreads();
        sh[t] += u; __syncthreads();
    }
    if (t < nb) bs[t] = sh[t] - v;   // exclusive
}

__global__ __launch_bounds__(256)
void scan_pass3(const int* __restrict__ deg, const int* __restrict__ bs,
                int* __restrict__ off, int n) {
    __shared__ int sh[256];
    int t = threadIdx.x;
    int base = blockIdx.x * 2048 + t * 8;
    int v[8]; int s = 0;
#pragma unroll
    for (int j = 0; j < 8; j++) { int idx = base + j; v[j] = (idx < n) ? deg[idx] : 0; s += v[j]; }
    sh[t] = s; __syncthreads();
    for (int st = 1; st < 256; st <<= 1) {
        int u = (t >= st) ? sh[t - st] : 0; __syncthreads();
        sh[t] += u; __syncthreads();
    }
    int acc = bs[blockIdx.x] + sh[t] - s;
#pragma unroll
    for (int j = 0; j < 8; j++) { int idx = base + j; if (idx < n) off[idx] = acc; acc += v[j]; }
}

// ---------------- scatter edges, 16 ranges over 2 launches, nt edge reads -----

__global__ __launch_bounds__(256)
void scatter_range_kernel(const int* __restrict__ src, const int* __restrict__ tgt,
                          int* __restrict__ cur2, int* __restrict__ nbr,
                          int n_nodes, int n_edges, int rsh, int rbase) {
    int r = rbase + (blockIdx.x & (NRANGE - 1));
    int chunk = blockIdx.x >> 3;
    int base = chunk * 2048;
#pragma unroll
    for (int j = 0; j < 8; j++) {
        int e = base + j * 256 + threadIdx.x;
        if (e < n_edges) {
            int t = __builtin_nontemporal_load(tgt + e);
            int s = __builtin_nontemporal_load(src + e);
            if ((t >> rsh) == r) { int p = atomicAdd(&cur2[t], 1);           nbr[p] = s; }
            if ((s >> rsh) == r) { int q = atomicAdd(&cur2[n_nodes + s], 1); nbr[q] = t; }
        }
    }
}

// ---------------- init: x (fp32) + xg (bf16 mirror), norms ----------------

__global__ __launch_bounds__(256)
void init_kernel(const int* __restrict__ nodes, const float* __restrict__ emb,
                 const int* __restrict__ deg2,
                 float* __restrict__ x, unsigned short* __restrict__ xg,
                 float* __restrict__ norm, float* __restrict__ norm_t, int n_nodes) {
    int gid = blockIdx.x * blockDim.x + threadIdx.x;
    int i = gid >> 5, c = gid & 31;
    if (i >= n_nodes) return;
    float v = emb[nodes[i] * CHANNELS + c];
    x[gid] = v;
    xg[gid] = (unsigned short)f2bf_rne(v);
    if (c == 0) {
        norm[i]   = 1.0f / (1.0f + (float)deg2[i]);
        norm_t[i] = 1.0f / (1.0f + (float)deg2[n_nodes + i]);
    }
}

// ---------------- counts via binary search over sorted batch ----------------

__global__ void counts_kernel(const int* __restrict__ batch, float* __restrict__ counts,
                              int n_nodes, int n_graphs) {
    int b = blockIdx.x * blockDim.x + threadIdx.x;
    if (b >= n_graphs) return;
    int lo = 0, hi = n_nodes;
    while (lo < hi) { int mid = (lo + hi) >> 1; if (batch[mid] < b) lo = mid + 1; else hi = mid; }
    int s = lo;
    lo = 0; hi = n_nodes;
    while (lo < hi) { int mid = (lo + hi) >> 1; if (batch[mid] < b + 1) lo = mid + 1; else hi = mid; }
    counts[b] = (float)(lo - s);
}

// ---------------- fused layer: node-parallel pipelined gather + MFMA ----------
// R7 structure verbatim; ONLY change: A and W LDS tiles padded to 40-short
// (80 B) rows so the MFMA-phase ds_read_b128 start banks are (20m+4q)%32 —
// 8 distinct starts per quad-group, <=2-way aliasing (free), vs 8-way at 64 B.

__global__ __launch_bounds__(256)
void layer_mfma(const int* __restrict__ off2, const int* __restrict__ nbr,
                const float* __restrict__ wbase,
                const float* __restrict__ norm, const float* __restrict__ norm_t,
                float* __restrict__ x,
                const unsigned short* __restrict__ xgin,
                unsigned short* __restrict__ xgout,
                int n_nodes, int n_edges) {
    __shared__ short A1h[64][APAD], A1l[64][APAD], A2h[64][APAD], A2l[64][APAD];
    __shared__ short W0h[32][APAD], W0l[32][APAD], W1h[32][APAD], W1l[32][APAD]; // [n][k]
    __shared__ int offIn[65], offOut[65];

    int tid = threadIdx.x;
    int nodeblock = blockIdx.x * 64;

    // stage weights (transpose + hi/lo split)
    for (int idx = tid; idx < CHANNELS * CHANNELS; idx += 256) {
        int k = idx >> 5, n = idx & 31;
        float w0 = wbase[idx];
        float w1 = wbase[CHANNELS * CHANNELS + idx];
        short h0 = f2bf_rne(w0); W0h[n][k] = h0; W0l[n][k] = f2bf_rne(w0 - bf2f(h0));
        short h1 = f2bf_rne(w1); W1h[n][k] = h1; W1l[n][k] = f2bf_rne(w1 - bf2f(h1));
    }
    // stage CSR offsets for this block's 64 nodes (both directions)
    if (tid < 65) {
        int idx = nodeblock + tid;
        offIn[tid]  = (idx <= n_nodes) ? off2[idx] : n_edges;
        int idx2 = n_nodes + idx;
        offOut[tid] = (idx2 < 2 * n_nodes) ? off2[idx2] : 2 * n_edges;
    }
    __syncthreads();

    int c = tid & 31, g = tid >> 5;

    // ---- pipelined pass state ----
    int bi_c, d1_c, bo_c, d2_c, nbl1_c, nbl2_c, node_c;
    float xv_c;
    {
        int local = g;
        node_c = nodeblock + local;
        bi_c = offIn[local];  d1_c = offIn[local + 1] - bi_c;
        bo_c = offOut[local]; d2_c = offOut[local + 1] - bo_c;
        nbl1_c = (c < d1_c) ? nbr[bi_c + c] : 0;
        nbl2_c = (c < d2_c) ? nbr[bo_c + c] : 0;
        xv_c = (node_c < n_nodes) ? x[node_c * CHANNELS + c] : 0.f;
    }

    for (int pass = 0; pass < 8; pass++) {
        // prefetch next pass's index rows + x row (lands during current gathers)
        int bi_n = 0, d1_n = 0, bo_n = 0, d2_n = 0, nbl1_n = 0, nbl2_n = 0, node_n = 0;
        float xv_n = 0.f;
        if (pass < 7) {
            int local = (pass + 1) * 8 + g;
            node_n = nodeblock + local;
            bi_n = offIn[local];  d1_n = offIn[local + 1] - bi_n;
            bo_n = offOut[local]; d2_n = offOut[local + 1] - bo_n;
            nbl1_n = (c < d1_n) ? nbr[bi_n + c] : 0;
            nbl2_n = (c < d2_n) ? nbr[bo_n + c] : 0;
            xv_n = (node_n < n_nodes) ? x[node_n * CHANNELS + c] : 0.f;
        }

        int local = pass * 8 + g;
        int i = node_c;
        int self = (i < n_nodes) ? i : 0;

        int m1 = d1_c < 32 ? d1_c : 32;
        int m2 = d2_c < 32 ? d2_c : 32;
        int mm = m1 > m2 ? m1 : m2;

        float a1 = 0.f, a2 = 0.f;
        for (int j = 0; j < mm; j += 4) {
            int p0 = __shfl(nbl1_c, (j)     & 31, 32);
            int p1 = __shfl(nbl1_c, (j + 1) & 31, 32);
            int p2 = __shfl(nbl1_c, (j + 2) & 31, 32);
            int p3 = __shfl(nbl1_c, (j + 3) & 31, 32);
            int q0 = __shfl(nbl2_c, (j)     & 31, 32);
            int q1 = __shfl(nbl2_c, (j + 1) & 31, 32);
            int q2 = __shfl(nbl2_c, (j + 2) & 31, 32);
            int q3 = __shfl(nbl2_c, (j + 3) & 31, 32);
            p0 = (j     < m1) ? p0 : self;
            p1 = (j + 1 < m1) ? p1 : self;
            p2 = (j + 2 < m1) ? p2 : self;
            p3 = (j + 3 < m1) ? p3 : self;
            q0 = (j     < m2) ? q0 : self;
            q1 = (j + 1 < m2) ? q1 : self;
            q2 = (j + 2 < m2) ? q2 : self;
            q3 = (j + 3 < m2) ? q3 : self;
            float u0 = bfu2f(xgin[p0 * CHANNELS + c]);
            float u1 = bfu2f(xgin[p1 * CHANNELS + c]);
            float u2 = bfu2f(xgin[p2 * CHANNELS + c]);
            float u3 = bfu2f(xgin[p3 * CHANNELS + c]);
            float w0 = bfu2f(xgin[q0 * CHANNELS + c]);
            float w1 = bfu2f(xgin[q1 * CHANNELS + c]);
            float w2 = bfu2f(xgin[q2 * CHANNELS + c]);
            float w3 = bfu2f(xgin[q3 * CHANNELS + c]);
            a1 += (j     < m1) ? u0 : 0.f;
            a1 += (j + 1 < m1) ? u1 : 0.f;
            a1 += (j + 2 < m1) ? u2 : 0.f;
            a1 += (j + 3 < m1) ? u3 : 0.f;
            a2 += (j     < m2) ? w0 : 0.f;
            a2 += (j + 1 < m2) ? w1 : 0.f;
            a2 += (j + 2 < m2) ? w2 : 0.f;
            a2 += (j + 3 < m2) ? w3 : 0.f;
        }
        // rare tails (degree > 32)
        for (int e = bi_c + 32; e < bi_c + d1_c; e++) a1 += bfu2f(xgin[nbr[e] * CHANNELS + c]);
        for (int e = bo_c + 32; e < bo_c + d2_c; e++) a2 += bfu2f(xgin[nbr[e] * CHANNELS + c]);

        if (i < n_nodes) {
            float n1 = norm[i], n2 = norm_t[i];
            a1 = n1 * (xv_c + a1);
            a2 = n2 * (xv_c + a2);
            short h1 = f2bf_rne(a1);
            A1h[local][c] = h1; A1l[local][c] = f2bf_rne(a1 - bf2f(h1));
            short h2 = f2bf_rne(a2);
            A2h[local][c] = h2; A2l[local][c] = f2bf_rne(a2 - bf2f(h2));
        } else {
            A1h[local][c] = 0; A1l[local][c] = 0;
            A2h[local][c] = 0; A2l[local][c] = 0;
        }

        // rotate pipeline
        bi_c = bi_n; d1_c = d1_n; bo_c = bo_n; d2_c = d2_n;
        nbl1_c = nbl1_n; nbl2_c = nbl2_n; xv_c = xv_n; node_c = node_n;
    }
    __syncthreads();

    // ----- MFMA + epilogue -----
    int wv = tid >> 6, lane = tid & 63;
    int m = lane & 15, quad = lane >> 4;
    int row0 = wv * 16;

    short8 a1h = *(const short8*)&A1h[row0 + m][quad * 8];
    short8 a1l = *(const short8*)&A1l[row0 + m][quad * 8];
    short8 a2h = *(const short8*)&A2h[row0 + m][quad * 8];
    short8 a2l = *(const short8*)&A2l[row0 + m][quad * 8];

    float4v dd[4];
#pragma unroll
    for (int h = 0; h < 2; h++) {
        int n0 = h * 16 + m;
        short8 b0h = *(const short8*)&W0h[n0][quad * 8];
        short8 b0l = *(const short8*)&W0l[n0][quad * 8];
        short8 b1h = *(const short8*)&W1h[n0][quad * 8];
        short8 b1l = *(const short8*)&W1l[n0][quad * 8];
        float4v d1 = {0.f, 0.f, 0.f, 0.f};
        d1 = __builtin_amdgcn_mfma_f32_16x16x32_bf16(a1h, b0h, d1, 0, 0, 0);
        d1 = __builtin_amdgcn_mfma_f32_16x16x32_bf16(a1l, b0h, d1, 0, 0, 0);
        d1 = __builtin_amdgcn_mfma_f32_16x16x32_bf16(a1h, b0l, d1, 0, 0, 0);
        float4v d2 = {0.f, 0.f, 0.f, 0.f};
        d2 = __builtin_amdgcn_mfma_f32_16x16x32_bf16(a2h, b1h, d2, 0, 0, 0);
        d2 = __builtin_amdgcn_mfma_f32_16x16x32_bf16(a2l, b1h, d2, 0, 0, 0);
        d2 = __builtin_amdgcn_mfma_f32_16x16x32_bf16(a2h, b1l, d2, 0, 0, 0);
        dd[h * 2] = d1; dd[h * 2 + 1] = d2;
    }

#pragma unroll
    for (int h = 0; h < 2; h++) {
        float4v d1 = dd[h * 2], d2 = dd[h * 2 + 1];
#pragma unroll
        for (int r = 0; r < 4; r++) {
            int local = row0 + quad * 4 + r;
            int node = nodeblock + local;
            if (node < n_nodes) {
                int col = h * 16 + m;
                float v = x[node * CHANNELS + col] + fmaxf(d1[r], 0.f) + fmaxf(d2[r], 0.f);
                x[node * CHANNELS + col] = v;
                xgout[node * CHANNELS + col] = (unsigned short)f2bf_rne(v);
            }
        }
    }
}

// ---------------- pooling: run-length accumulate over sorted batch ----------------

#define POOL_CHUNK 2048

__global__ __launch_bounds__(256)
void pool_kernel(const int* __restrict__ batch, const float* __restrict__ x,
                 float* __restrict__ g, int n_nodes) {
    int c = threadIdx.x & 31;
    int r = threadIdx.x >> 5;
    int base = blockIdx.x * POOL_CHUNK;
    float acc = 0.f;
    int cur = -1;
    for (int it = 0; it < POOL_CHUNK / 8; it++) {
        int node = base + it * 8 + r;
        if (node >= n_nodes) break;
        int b = batch[node];
        if (b != cur) {
            if (cur >= 0) atomicAdd(&g[cur * CHANNELS + c], acc);
            acc = 0.f;
            cur = b;
        }
        acc += x[node * CHANNELS + c];
    }
    if (cur >= 0) atomicAdd(&g[cur * CHANNELS + c], acc);
}

// ---------------- MLP head: one block per graph ----------------

__global__ __launch_bounds__(256)
void mlp_kernel(const float* __restrict__ g, const float* __restrict__ counts,
                const float* __restrict__ hidden_w, const float* __restrict__ hidden_b,
                const float* __restrict__ out_w, float* __restrict__ out) {
    __shared__ float grow[CHANNELS];
    __shared__ float red[256];
    int graph = blockIdx.x;
    int tid = threadIdx.x;
    if (tid < CHANNELS) grow[tid] = g[graph * CHANNELS + tid] / counts[graph];
    __syncthreads();
    float partial = 0.f;
    for (int q = 0; q < HIDDEN / 256; q++) {
        int j = q * 256 + tid;
        float h = hidden_b[j];
#pragma unroll
        for (int k = 0; k < CHANNELS; k++) h += grow[k] * hidden_w[k * HIDDEN + j];
        partial += fmaxf(h, 0.f) * out_w[j];
    }
    red[tid] = partial;
    __syncthreads();
    for (int s = 128; s > 0; s >>= 1) {
        if (tid < s) red[tid] += red[tid + s];
        __syncthreads();
    }
    if (tid == 0) out[graph] = red[0];
}

// ---------------- launch ----------------

extern "C" void kernel_launch(void* const* d_in, const int* in_sizes, int n_in,
                              void* d_out, int out_size, void* d_ws, size_t ws_size,
                              hipStream_t stream) {
    const int*   nodes    = (const int*)d_in[0];
    const int*   sources  = (const int*)d_in[1];
    const int*   targets  = (const int*)d_in[2];
    const int*   batch    = (const int*)d_in[3];
    const float* emb      = (const float*)d_in[4];
    const float* conv_w   = (const float*)d_in[5];
    const float* hidden_w = (const float*)d_in[6];
    const float* hidden_b = (const float*)d_in[7];
    const float* out_w    = (const float*)d_in[8];
    float* out = (float*)d_out;

    const int n_nodes  = in_sizes[0];
    const int n_edges  = in_sizes[1];
    const int n_graphs = out_size;
    const int n2 = 2 * n_nodes;

    int rsh8 = 0;
    while (((n_nodes - 1) >> rsh8) >= 8) rsh8++;
    int rsh16 = 0;
    while (((n_nodes - 1) >> rsh16) >= 16) rsh16++;

    char* ws = (char*)d_ws;
    float*          x      = (float*)ws;          ws += (size_t)n_nodes * CHANNELS * 4;
    unsigned short* xg0    = (unsigned short*)ws; ws += (size_t)n_nodes * CHANNELS * 2;
    unsigned short* xg1    = (unsigned short*)ws; ws += (size_t)n_nodes * CHANNELS * 2;
    float* norm   = (float*)ws; ws += (size_t)n_nodes * 4;
    float* norm_t = (float*)ws; ws += (size_t)n_nodes * 4;
    int*   deg2   = (int*)ws;   ws += (size_t)n2 * 4;
    int*   off2   = (int*)ws;   ws += (size_t)n2 * 4;
    int*   cur2   = (int*)ws;   ws += (size_t)n2 * 4;
    int*   nbr    = (int*)ws;   ws += (size_t)2 * n_edges * 4;
    int*   bsums  = (int*)ws;   ws += 4096;
    float* g      = (float*)ws; ws += (size_t)n_graphs * CHANNELS * 4;
    float* counts = (float*)ws; ws += (size_t)n_graphs * 4;

    hipMemsetAsync(deg2, 0, (size_t)n2 * 4, stream);
    hipMemsetAsync(g, 0, (size_t)n_graphs * CHANNELS * 4, stream);

    int echunks = (n_edges + 2047) / 2048;

    // 1. degrees (8 ranges, XCD-affine, nt edge reads)
    deg_range_kernel<<<echunks * NRANGE, 256, 0, stream>>>(sources, targets, deg2,
                                                           n_nodes, n_edges, rsh8);

    // 2. exclusive scan deg2 -> off2
    int nblk = (n2 + 2047) / 2048;
    scan_pass1<<<nblk, 256, 0, stream>>>(deg2, bsums, n2);
    scan_pass2<<<1, 1024, 0, stream>>>(bsums, nblk);
    scan_pass3<<<nblk, 256, 0, stream>>>(deg2, bsums, off2, n2);

    // 3. cursors = offsets copy, then scatter (16 ranges over 2 launches)
    hipMemcpyAsync(cur2, off2, (size_t)n2 * 4, hipMemcpyDeviceToDevice, stream);
    scatter_range_kernel<<<echunks * NRANGE, 256, 0, stream>>>(sources, targets, cur2, nbr,
                                                               n_nodes, n_edges, rsh16, 0);
    scatter_range_kernel<<<echunks * NRANGE, 256, 0, stream>>>(sources, targets, cur2, nbr,
                                                               n_nodes, n_edges, rsh16, 8);

    // 4. init features + norms; counts via binary search
    int node_thr = n_nodes * CHANNELS;
    init_kernel<<<(node_thr + 255) / 256, 256, 0, stream>>>(nodes, emb, deg2, x, xg0,
                                                            norm, norm_t, n_nodes);
    counts_kernel<<<(n_graphs + 255) / 256, 256, 0, stream>>>(batch, counts, n_nodes, n_graphs);

    // 5. layers: fp32 x in place, bf16 mirror ping-pongs
    unsigned short* xgin = xg0; unsigned short* xgout = xg1;
    int lblocks = (n_nodes + 63) / 64;
    for (int l = 0; l < LAYERS; l++) {
        const float* wbase = conv_w + (size_t)l * 2 * CHANNELS * CHANNELS;
        layer_mfma<<<lblocks, 256, 0, stream>>>(off2, nbr, wbase, norm, norm_t,
                                                x, xgin, xgout, n_nodes, n_edges);
        unsigned short* tmp = xgin; xgin = xgout; xgout = tmp;
    }

    // 6. pool + head
    int pool_blocks = (n_nodes + POOL_CHUNK - 1) / POOL_CHUNK;
    pool_kernel<<<pool_blocks, 256, 0, stream>>>(batch, x, g, n_nodes);
    mlp_kernel<<<n_graphs, 256, 0, stream>>>(g, counts, hidden_w, hidden_b, out_w, out);
}

// Round 11
// 1616.371 us; speedup vs baseline: 1.1869x; 1.1281x over previous
//
#include <hip/hip_runtime.h>

#define CHANNELS 32
#define HIDDEN 1024
#define LAYERS 8
#define NRANGE 8

typedef __attribute__((ext_vector_type(8))) short short8;
typedef __attribute__((ext_vector_type(4))) float float4v;

__device__ __forceinline__ short f2bf_rne(float f) {
    union { float f; unsigned u; } v; v.f = f;
    unsigned r = v.u + 0x7fffu + ((v.u >> 16) & 1u);
    return (short)(r >> 16);
}
__device__ __forceinline__ float bfu2f(unsigned short h) {
    union { float f; unsigned u; } v; v.u = ((unsigned)h) << 16;
    return v.f;
}

// ---------------- degree count, range-split (XCD-affine), nt edge reads -------

__global__ __launch_bounds__(256)
void deg_range_kernel(const int* __restrict__ src, const int* __restrict__ tgt,
                      int* __restrict__ deg2, int n_nodes, int n_edges, int rsh) {
    int r = blockIdx.x & (NRANGE - 1);
    int chunk = blockIdx.x >> 3;
    int base = chunk * 2048;
#pragma unroll
    for (int j = 0; j < 8; j++) {
        int e = base + j * 256 + threadIdx.x;
        if (e < n_edges) {
            int t = __builtin_nontemporal_load(tgt + e);
            int s = __builtin_nontemporal_load(src + e);
            if ((t >> rsh) == r) atomicAdd(&deg2[t], 1);
            if ((s >> rsh) == r) atomicAdd(&deg2[n_nodes + s], 1);
        }
    }
}

// ---------------- 3-kernel exclusive prefix scan over deg2[0..n2) ----------------

__global__ __launch_bounds__(256)
void scan_pass1(const int* __restrict__ deg, int* __restrict__ bs, int n) {
    __shared__ int sh[256];
    int t = threadIdx.x;
    int base = blockIdx.x * 2048 + t * 8;
    int s = 0;
#pragma unroll
    for (int j = 0; j < 8; j++) { int idx = base + j; if (idx < n) s += deg[idx]; }
    sh[t] = s; __syncthreads();
    for (int st = 128; st > 0; st >>= 1) { if (t < st) sh[t] += sh[t + st]; __syncthreads(); }
    if (t == 0) bs[blockIdx.x] = sh[0];
}

__global__ void scan_pass2(int* __restrict__ bs, int nb) {
    __shared__ int sh[1024];
    int t = threadIdx.x;
    int v = (t < nb) ? bs[t] : 0;
    sh[t] = v; __syncthreads();
    for (int off = 1; off < 1024; off <<= 1) {
        int u = (t >= off) ? sh[t - off] : 0; __syncthreads();
        sh[t] += u; __syncthreads();
    }
    if (t < nb) bs[t] = sh[t] - v;   // exclusive
}

__global__ __launch_bounds__(256)
void scan_pass3(const int* __restrict__ deg, const int* __restrict__ bs,
                int* __restrict__ off, int n) {
    __shared__ int sh[256];
    int t = threadIdx.x;
    int base = blockIdx.x * 2048 + t * 8;
    int v[8]; int s = 0;
#pragma unroll
    for (int j = 0; j < 8; j++) { int idx = base + j; v[j] = (idx < n) ? deg[idx] : 0; s += v[j]; }
    sh[t] = s; __syncthreads();
    for (int st = 1; st < 256; st <<= 1) {
        int u = (t >= st) ? sh[t - st] : 0; __syncthreads();
        sh[t] += u; __syncthreads();
    }
    int acc = bs[blockIdx.x] + sh[t] - s;
#pragma unroll
    for (int j = 0; j < 8; j++) { int idx = base + j; if (idx < n) off[idx] = acc; acc += v[j]; }
}

// ---------------- scatter edges, 16 ranges over 2 launches, nt edge reads -----

__global__ __launch_bounds__(256)
void scatter_range_kernel(const int* __restrict__ src, const int* __restrict__ tgt,
                          int* __restrict__ cur2, int* __restrict__ nbr,
                          int n_nodes, int n_edges, int rsh, int rbase) {
    int r = rbase + (blockIdx.x & (NRANGE - 1));
    int chunk = blockIdx.x >> 3;
    int base = chunk * 2048;
#pragma unroll
    for (int j = 0; j < 8; j++) {
        int e = base + j * 256 + threadIdx.x;
        if (e < n_edges) {
            int t = __builtin_nontemporal_load(tgt + e);
            int s = __builtin_nontemporal_load(src + e);
            if ((t >> rsh) == r) { int p = atomicAdd(&cur2[t], 1);           nbr[p] = s; }
            if ((s >> rsh) == r) { int q = atomicAdd(&cur2[n_nodes + s], 1); nbr[q] = t; }
        }
    }
}

// ---------------- init: x (fp32) + xg (bf16 mirror), norms ----------------

__global__ __launch_bounds__(256)
void init_kernel(const int* __restrict__ nodes, const float* __restrict__ emb,
                 const int* __restrict__ deg2,
                 float* __restrict__ x, unsigned short* __restrict__ xg,
                 float* __restrict__ norm, float* __restrict__ norm_t, int n_nodes) {
    int gid = blockIdx.x * blockDim.x + threadIdx.x;
    int i = gid >> 5, c = gid & 31;
    if (i >= n_nodes) return;
    float v = emb[nodes[i] * CHANNELS + c];
    x[gid] = v;
    xg[gid] = (unsigned short)f2bf_rne(v);
    if (c == 0) {
        norm[i]   = 1.0f / (1.0f + (float)deg2[i]);
        norm_t[i] = 1.0f / (1.0f + (float)deg2[n_nodes + i]);
    }
}

// ---------------- counts via binary search over sorted batch ----------------

__global__ void counts_kernel(const int* __restrict__ batch, float* __restrict__ counts,
                              int n_nodes, int n_graphs) {
    int b = blockIdx.x * blockDim.x + threadIdx.x;
    if (b >= n_graphs) return;
    int lo = 0, hi = n_nodes;
    while (lo < hi) { int mid = (lo + hi) >> 1; if (batch[mid] < b) lo = mid + 1; else hi = mid; }
    int s = lo;
    lo = 0; hi = n_nodes;
    while (lo < hi) { int mid = (lo + hi) >> 1; if (batch[mid] < b + 1) lo = mid + 1; else hi = mid; }
    counts[b] = (float)(lo - s);
}

// ---------------- fused layer: node-parallel pipelined gather + bf16 MFMA -----
// R7 structure; pure-bf16 fragments (no hi/lo split): LDS ~13 KB -> 8 blocks/CU
// (32 waves, HW cap) for max latency hiding of the random L3 row gathers.
// __launch_bounds__(256,8) holds VGPR <= 64 for that occupancy.

__global__ __launch_bounds__(256, 8)
void layer_mfma(const int* __restrict__ off2, const int* __restrict__ nbr,
                const float* __restrict__ wbase,
                const float* __restrict__ norm, const float* __restrict__ norm_t,
                float* __restrict__ x,
                const unsigned short* __restrict__ xgin,
                unsigned short* __restrict__ xgout,
                int n_nodes, int n_edges) {
    __shared__ short A1h[64][32], A2h[64][32];
    __shared__ short W0h[32][32], W1h[32][32]; // [n][k]
    __shared__ int offIn[65], offOut[65];

    int tid = threadIdx.x;
    int nodeblock = blockIdx.x * 64;

    // stage weights (transpose, bf16)
    for (int idx = tid; idx < CHANNELS * CHANNELS; idx += 256) {
        int k = idx >> 5, n = idx & 31;
        W0h[n][k] = f2bf_rne(wbase[idx]);
        W1h[n][k] = f2bf_rne(wbase[CHANNELS * CHANNELS + idx]);
    }
    // stage CSR offsets for this block's 64 nodes (both directions)
    if (tid < 65) {
        int idx = nodeblock + tid;
        offIn[tid]  = (idx <= n_nodes) ? off2[idx] : n_edges;
        int idx2 = n_nodes + idx;
        offOut[tid] = (idx2 < 2 * n_nodes) ? off2[idx2] : 2 * n_edges;
    }
    __syncthreads();

    int c = tid & 31, g = tid >> 5;

    // ---- pipelined pass state ----
    int bi_c, d1_c, bo_c, d2_c, nbl1_c, nbl2_c, node_c;
    float xv_c;
    {
        int local = g;
        node_c = nodeblock + local;
        bi_c = offIn[local];  d1_c = offIn[local + 1] - bi_c;
        bo_c = offOut[local]; d2_c = offOut[local + 1] - bo_c;
        nbl1_c = (c < d1_c) ? nbr[bi_c + c] : 0;
        nbl2_c = (c < d2_c) ? nbr[bo_c + c] : 0;
        xv_c = (node_c < n_nodes) ? x[node_c * CHANNELS + c] : 0.f;
    }

    for (int pass = 0; pass < 8; pass++) {
        // prefetch next pass's index rows + x row (lands during current gathers)
        int bi_n = 0, d1_n = 0, bo_n = 0, d2_n = 0, nbl1_n = 0, nbl2_n = 0, node_n = 0;
        float xv_n = 0.f;
        if (pass < 7) {
            int local = (pass + 1) * 8 + g;
            node_n = nodeblock + local;
            bi_n = offIn[local];  d1_n = offIn[local + 1] - bi_n;
            bo_n = offOut[local]; d2_n = offOut[local + 1] - bo_n;
            nbl1_n = (c < d1_n) ? nbr[bi_n + c] : 0;
            nbl2_n = (c < d2_n) ? nbr[bo_n + c] : 0;
            xv_n = (node_n < n_nodes) ? x[node_n * CHANNELS + c] : 0.f;
        }

        int local = pass * 8 + g;
        int i = node_c;
        int self = (i < n_nodes) ? i : 0;

        int m1 = d1_c < 32 ? d1_c : 32;
        int m2 = d2_c < 32 ? d2_c : 32;
        int mm = m1 > m2 ? m1 : m2;

        float a1 = 0.f, a2 = 0.f;
        for (int j = 0; j < mm; j += 4) {
            int p0 = __shfl(nbl1_c, (j)     & 31, 32);
            int p1 = __shfl(nbl1_c, (j + 1) & 31, 32);
            int p2 = __shfl(nbl1_c, (j + 2) & 31, 32);
            int p3 = __shfl(nbl1_c, (j + 3) & 31, 32);
            int q0 = __shfl(nbl2_c, (j)     & 31, 32);
            int q1 = __shfl(nbl2_c, (j + 1) & 31, 32);
            int q2 = __shfl(nbl2_c, (j + 2) & 31, 32);
            int q3 = __shfl(nbl2_c, (j + 3) & 31, 32);
            p0 = (j     < m1) ? p0 : self;
            p1 = (j + 1 < m1) ? p1 : self;
            p2 = (j + 2 < m1) ? p2 : self;
            p3 = (j + 3 < m1) ? p3 : self;
            q0 = (j     < m2) ? q0 : self;
            q1 = (j + 1 < m2) ? q1 : self;
            q2 = (j + 2 < m2) ? q2 : self;
            q3 = (j + 3 < m2) ? q3 : self;
            float u0 = bfu2f(xgin[p0 * CHANNELS + c]);
            float u1 = bfu2f(xgin[p1 * CHANNELS + c]);
            float u2 = bfu2f(xgin[p2 * CHANNELS + c]);
            float u3 = bfu2f(xgin[p3 * CHANNELS + c]);
            float w0 = bfu2f(xgin[q0 * CHANNELS + c]);
            float w1 = bfu2f(xgin[q1 * CHANNELS + c]);
            float w2 = bfu2f(xgin[q2 * CHANNELS + c]);
            float w3 = bfu2f(xgin[q3 * CHANNELS + c]);
            a1 += (j     < m1) ? u0 : 0.f;
            a1 += (j + 1 < m1) ? u1 : 0.f;
            a1 += (j + 2 < m1) ? u2 : 0.f;
            a1 += (j + 3 < m1) ? u3 : 0.f;
            a2 += (j     < m2) ? w0 : 0.f;
            a2 += (j + 1 < m2) ? w1 : 0.f;
            a2 += (j + 2 < m2) ? w2 : 0.f;
            a2 += (j + 3 < m2) ? w3 : 0.f;
        }
        // rare tails (degree > 32)
        for (int e = bi_c + 32; e < bi_c + d1_c; e++) a1 += bfu2f(xgin[nbr[e] * CHANNELS + c]);
        for (int e = bo_c + 32; e < bo_c + d2_c; e++) a2 += bfu2f(xgin[nbr[e] * CHANNELS + c]);

        if (i < n_nodes) {
            float n1 = norm[i], n2 = norm_t[i];
            a1 = n1 * (xv_c + a1);
            a2 = n2 * (xv_c + a2);
            A1h[local][c] = f2bf_rne(a1);
            A2h[local][c] = f2bf_rne(a2);
        } else {
            A1h[local][c] = 0;
            A2h[local][c] = 0;
        }

        // rotate pipeline
        bi_c = bi_n; d1_c = d1_n; bo_c = bo_n; d2_c = d2_n;
        nbl1_c = nbl1_n; nbl2_c = nbl2_n; xv_c = xv_n; node_c = node_n;
    }
    __syncthreads();

    // ----- MFMA + epilogue -----
    int wv = tid >> 6, lane = tid & 63;
    int m = lane & 15, quad = lane >> 4;
    int row0 = wv * 16;

    short8 a1h = *(const short8*)&A1h[row0 + m][quad * 8];
    short8 a2h = *(const short8*)&A2h[row0 + m][quad * 8];

    float4v dd[4];
#pragma unroll
    for (int h = 0; h < 2; h++) {
        int n0 = h * 16 + m;
        short8 b0h = *(const short8*)&W0h[n0][quad * 8];
        short8 b1h = *(const short8*)&W1h[n0][quad * 8];
        float4v d1 = {0.f, 0.f, 0.f, 0.f};
        d1 = __builtin_amdgcn_mfma_f32_16x16x32_bf16(a1h, b0h, d1, 0, 0, 0);
        float4v d2 = {0.f, 0.f, 0.f, 0.f};
        d2 = __builtin_amdgcn_mfma_f32_16x16x32_bf16(a2h, b1h, d2, 0, 0, 0);
        dd[h * 2] = d1; dd[h * 2 + 1] = d2;
    }

#pragma unroll
    for (int h = 0; h < 2; h++) {
        float4v d1 = dd[h * 2], d2 = dd[h * 2 + 1];
#pragma unroll
        for (int r = 0; r < 4; r++) {
            int local = row0 + quad * 4 + r;
            int node = nodeblock + local;
            if (node < n_nodes) {
                int col = h * 16 + m;
                float v = x[node * CHANNELS + col] + fmaxf(d1[r], 0.f) + fmaxf(d2[r], 0.f);
                x[node * CHANNELS + col] = v;
                xgout[node * CHANNELS + col] = (unsigned short)f2bf_rne(v);
            }
        }
    }
}

// ---------------- pooling: run-length accumulate over sorted batch ----------------

#define POOL_CHUNK 2048

__global__ __launch_bounds__(256)
void pool_kernel(const int* __restrict__ batch, const float* __restrict__ x,
                 float* __restrict__ g, int n_nodes) {
    int c = threadIdx.x & 31;
    int r = threadIdx.x >> 5;
    int base = blockIdx.x * POOL_CHUNK;
    float acc = 0.f;
    int cur = -1;
    for (int it = 0; it < POOL_CHUNK / 8; it++) {
        int node = base + it * 8 + r;
        if (node >= n_nodes) break;
        int b = batch[node];
        if (b != cur) {
            if (cur >= 0) atomicAdd(&g[cur * CHANNELS + c], acc);
            acc = 0.f;
            cur = b;
        }
        acc += x[node * CHANNELS + c];
    }
    if (cur >= 0) atomicAdd(&g[cur * CHANNELS + c], acc);
}

// ---------------- MLP head: one block per graph ----------------

__global__ __launch_bounds__(256)
void mlp_kernel(const float* __restrict__ g, const float* __restrict__ counts,
                const float* __restrict__ hidden_w, const float* __restrict__ hidden_b,
                const float* __restrict__ out_w, float* __restrict__ out) {
    __shared__ float grow[CHANNELS];
    __shared__ float red[256];
    int graph = blockIdx.x;
    int tid = threadIdx.x;
    if (tid < CHANNELS) grow[tid] = g[graph * CHANNELS + tid] / counts[graph];
    __syncthreads();
    float partial = 0.f;
    for (int q = 0; q < HIDDEN / 256; q++) {
        int j = q * 256 + tid;
        float h = hidden_b[j];
#pragma unroll
        for (int k = 0; k < CHANNELS; k++) h += grow[k] * hidden_w[k * HIDDEN + j];
        partial += fmaxf(h, 0.f) * out_w[j];
    }
    red[tid] = partial;
    __syncthreads();
    for (int s = 128; s > 0; s >>= 1) {
        if (tid < s) red[tid] += red[tid + s];
        __syncthreads();
    }
    if (tid == 0) out[graph] = red[0];
}

// ---------------- launch ----------------

extern "C" void kernel_launch(void* const* d_in, const int* in_sizes, int n_in,
                              void* d_out, int out_size, void* d_ws, size_t ws_size,
                              hipStream_t stream) {
    const int*   nodes    = (const int*)d_in[0];
    const int*   sources  = (const int*)d_in[1];
    const int*   targets  = (const int*)d_in[2];
    const int*   batch    = (const int*)d_in[3];
    const float* emb      = (const float*)d_in[4];
    const float* conv_w   = (const float*)d_in[5];
    const float* hidden_w = (const float*)d_in[6];
    const float* hidden_b = (const float*)d_in[7];
    const float* out_w    = (const float*)d_in[8];
    float* out = (float*)d_out;

    const int n_nodes  = in_sizes[0];
    const int n_edges  = in_sizes[1];
    const int n_graphs = out_size;
    const int n2 = 2 * n_nodes;

    int rsh8 = 0;
    while (((n_nodes - 1) >> rsh8) >= 8) rsh8++;
    int rsh16 = 0;
    while (((n_nodes - 1) >> rsh16) >= 16) rsh16++;

    char* ws = (char*)d_ws;
    float*          x      = (float*)ws;          ws += (size_t)n_nodes * CHANNELS * 4;
    unsigned short* xg0    = (unsigned short*)ws; ws += (size_t)n_nodes * CHANNELS * 2;
    unsigned short* xg1    = (unsigned short*)ws; ws += (size_t)n_nodes * CHANNELS * 2;
    float* norm   = (float*)ws; ws += (size_t)n_nodes * 4;
    float* norm_t = (float*)ws; ws += (size_t)n_nodes * 4;
    int*   deg2   = (int*)ws;   ws += (size_t)n2 * 4;
    int*   off2   = (int*)ws;   ws += (size_t)n2 * 4;
    int*   cur2   = (int*)ws;   ws += (size_t)n2 * 4;
    int*   nbr    = (int*)ws;   ws += (size_t)2 * n_edges * 4;
    int*   bsums  = (int*)ws;   ws += 4096;
    float* g      = (float*)ws; ws += (size_t)n_graphs * CHANNELS * 4;
    float* counts = (float*)ws; ws += (size_t)n_graphs * 4;

    hipMemsetAsync(deg2, 0, (size_t)n2 * 4, stream);
    hipMemsetAsync(g, 0, (size_t)n_graphs * CHANNELS * 4, stream);

    int echunks = (n_edges + 2047) / 2048;

    // 1. degrees (8 ranges, XCD-affine, nt edge reads)
    deg_range_kernel<<<echunks * NRANGE, 256, 0, stream>>>(sources, targets, deg2,
                                                           n_nodes, n_edges, rsh8);

    // 2. exclusive scan deg2 -> off2
    int nblk = (n2 + 2047) / 2048;
    scan_pass1<<<nblk, 256, 0, stream>>>(deg2, bsums, n2);
    scan_pass2<<<1, 1024, 0, stream>>>(bsums, nblk);
    scan_pass3<<<nblk, 256, 0, stream>>>(deg2, bsums, off2, n2);

    // 3. cursors = offsets copy, then scatter (16 ranges over 2 launches)
    hipMemcpyAsync(cur2, off2, (size_t)n2 * 4, hipMemcpyDeviceToDevice, stream);
    scatter_range_kernel<<<echunks * NRANGE, 256, 0, stream>>>(sources, targets, cur2, nbr,
                                                               n_nodes, n_edges, rsh16, 0);
    scatter_range_kernel<<<echunks * NRANGE, 256, 0, stream>>>(sources, targets, cur2, nbr,
                                                               n_nodes, n_edges, rsh16, 8);

    // 4. init features + norms; counts via binary search
    int node_thr = n_nodes * CHANNELS;
    init_kernel<<<(node_thr + 255) / 256, 256, 0, stream>>>(nodes, emb, deg2, x, xg0,
                                                            norm, norm_t, n_nodes);
    counts_kernel<<<(n_graphs + 255) / 256, 256, 0, stream>>>(batch, counts, n_nodes, n_graphs);

    // 5. layers: fp32 x in place, bf16 mirror ping-pongs
    unsigned short* xgin = xg0; unsigned short* xgout = xg1;
    int lblocks = (n_nodes + 63) / 64;
    for (int l = 0; l < LAYERS; l++) {
        const float* wbase = conv_w + (size_t)l * 2 * CHANNELS * CHANNELS;
        layer_mfma<<<lblocks, 256, 0, stream>>>(off2, nbr, wbase, norm, norm_t,
                                                x, xgin, xgout, n_nodes, n_edges);
        unsigned short* tmp = xgin; xgin = xgout; xgout = tmp;
    }

    // 6. pool + head
    int pool_blocks = (n_nodes + POOL_CHUNK - 1) / POOL_CHUNK;
    pool_kernel<<<pool_blocks, 256, 0, stream>>>(batch, x, g, n_nodes);
    mlp_kernel<<<n_graphs, 256, 0, stream>>>(g, counts, hidden_w, hidden_b, out_w, out);
}

// Round 12
// 1529.056 us; speedup vs baseline: 1.2547x; 1.0571x over previous
//
#include <hip/hip_runtime.h>

#define CHANNELS 32
#define HIDDEN 1024
#define LAYERS 8
#define NRANGE 8

typedef __attribute__((ext_vector_type(8))) short short8;
typedef __attribute__((ext_vector_type(4))) float float4v;

__device__ __forceinline__ short f2bf_rne(float f) {
    union { float f; unsigned u; } v; v.f = f;
    unsigned r = v.u + 0x7fffu + ((v.u >> 16) & 1u);
    return (short)(r >> 16);
}
__device__ __forceinline__ float bf2f(short h) {
    union { float f; unsigned u; } v; v.u = ((unsigned)(unsigned short)h) << 16;
    return v.f;
}
__device__ __forceinline__ float bfu2f(unsigned short h) {
    union { float f; unsigned u; } v; v.u = ((unsigned)h) << 16;
    return v.f;
}

// ------- fused pre-pass: degree count + feature init (hi/lo planes) + counts --
// Independent jobs selected by blockIdx: [0,degB) degree atomics (range-split),
// [degB,degB+initB) embedding init, tail counts-binary-search. Norms are NOT
// precomputed: the layer derives them from CSR offsets.

__global__ __launch_bounds__(256)
void pre_kernel(const int* __restrict__ src, const int* __restrict__ tgt,
                int* __restrict__ deg2,
                const int* __restrict__ nodes, const float* __restrict__ emb,
                unsigned short* __restrict__ hi0, unsigned short* __restrict__ lo,
                const int* __restrict__ batch, float* __restrict__ counts,
                int n_nodes, int n_edges, int n_graphs, int rsh,
                int degB, int initB) {
    int bid = blockIdx.x;
    int tid = threadIdx.x;
    if (bid < degB) {
        int r = bid & (NRANGE - 1);
        int chunk = bid >> 3;
        int base = chunk * 2048;
#pragma unroll
        for (int j = 0; j < 8; j++) {
            int e = base + j * 256 + tid;
            if (e < n_edges) {
                int t = __builtin_nontemporal_load(tgt + e);
                int s = __builtin_nontemporal_load(src + e);
                if ((t >> rsh) == r) atomicAdd(&deg2[t], 1);
                if ((s >> rsh) == r) atomicAdd(&deg2[n_nodes + s], 1);
            }
        }
    } else if (bid < degB + initB) {
        int gid = (bid - degB) * 256 + tid;
        int i = gid >> 5, c = gid & 31;
        if (i < n_nodes) {
            float v = emb[nodes[i] * CHANNELS + c];
            short h = f2bf_rne(v);
            hi0[gid] = (unsigned short)h;
            lo[gid]  = (unsigned short)f2bf_rne(v - bf2f(h));
        }
    } else {
        int b = (bid - degB - initB) * 256 + tid;
        if (b < n_graphs) {
            int lo_i = 0, hi_i = n_nodes;
            while (lo_i < hi_i) { int mid = (lo_i + hi_i) >> 1; if (batch[mid] < b) lo_i = mid + 1; else hi_i = mid; }
            int s0 = lo_i;
            lo_i = 0; hi_i = n_nodes;
            while (lo_i < hi_i) { int mid = (lo_i + hi_i) >> 1; if (batch[mid] < b + 1) lo_i = mid + 1; else hi_i = mid; }
            counts[b] = (float)(lo_i - s0);
        }
    }
}

// ---------------- 3-kernel exclusive prefix scan over deg2[0..n2) ----------------

__global__ __launch_bounds__(256)
void scan_pass1(const int* __restrict__ deg, int* __restrict__ bs, int n) {
    __shared__ int sh[256];
    int t = threadIdx.x;
    int base = blockIdx.x * 2048 + t * 8;
    int s = 0;
#pragma unroll
    for (int j = 0; j < 8; j++) { int idx = base + j; if (idx < n) s += deg[idx]; }
    sh[t] = s; __syncthreads();
    for (int st = 128; st > 0; st >>= 1) { if (t < st) sh[t] += sh[t + st]; __syncthreads(); }
    if (t == 0) bs[blockIdx.x] = sh[0];
}

__global__ void scan_pass2(int* __restrict__ bs, int nb) {
    __shared__ int sh[1024];
    int t = threadIdx.x;
    int v = (t < nb) ? bs[t] : 0;
    sh[t] = v; __syncthreads();
    for (int off = 1; off < 1024; off <<= 1) {
        int u = (t >= off) ? sh[t - off] : 0; __syncthreads();
        sh[t] += u; __syncthreads();
    }
    if (t < nb) bs[t] = sh[t] - v;   // exclusive
}

__global__ __launch_bounds__(256)
void scan_pass3(const int* __restrict__ deg, const int* __restrict__ bs,
                int* __restrict__ off, int n) {
    __shared__ int sh[256];
    int t = threadIdx.x;
    int base = blockIdx.x * 2048 + t * 8;
    int v[8]; int s = 0;
#pragma unroll
    for (int j = 0; j < 8; j++) { int idx = base + j; v[j] = (idx < n) ? deg[idx] : 0; s += v[j]; }
    sh[t] = s; __syncthreads();
    for (int st = 1; st < 256; st <<= 1) {
        int u = (t >= st) ? sh[t - st] : 0; __syncthreads();
        sh[t] += u; __syncthreads();
    }
    int acc = bs[blockIdx.x] + sh[t] - s;
#pragma unroll
    for (int j = 0; j < 8; j++) { int idx = base + j; if (idx < n) off[idx] = acc; acc += v[j]; }
}

// ---------------- scatter edges, 16 ranges over 2 launches, nt edge reads -----

__global__ __launch_bounds__(256)
void scatter_range_kernel(const int* __restrict__ src, const int* __restrict__ tgt,
                          int* __restrict__ cur2, int* __restrict__ nbr,
                          int n_nodes, int n_edges, int rsh, int rbase) {
    int r = rbase + (blockIdx.x & (NRANGE - 1));
    int chunk = blockIdx.x >> 3;
    int base = chunk * 2048;
#pragma unroll
    for (int j = 0; j < 8; j++) {
        int e = base + j * 256 + threadIdx.x;
        if (e < n_edges) {
            int t = __builtin_nontemporal_load(tgt + e);
            int s = __builtin_nontemporal_load(src + e);
            if ((t >> rsh) == r) { int p = atomicAdd(&cur2[t], 1);           nbr[p] = s; }
            if ((s >> rsh) == r) { int q = atomicAdd(&cur2[n_nodes + s], 1); nbr[q] = t; }
        }
    }
}

// ---------------- fused layer: node-parallel pipelined gather + bf16 MFMA -----
// x is stored as bf16 planes: hi (ping-pong, gathered by neighbors) + lo
// (in-place, owner-only); hi+lo ~= fp32 residual. Norms derived from CSR
// degrees in-kernel. LDS ~13 KB -> 8 blocks/CU.

__global__ __launch_bounds__(256, 8)
void layer_mfma(const int* __restrict__ off2, const int* __restrict__ nbr,
                const float* __restrict__ wbase,
                const unsigned short* __restrict__ hi_in,
                unsigned short* __restrict__ hi_out,
                unsigned short* __restrict__ lo,
                int n_nodes, int n_edges) {
    __shared__ short A1h[64][32], A2h[64][32];
    __shared__ short W0h[32][32], W1h[32][32]; // [n][k]
    __shared__ int offIn[65], offOut[65];

    int tid = threadIdx.x;
    int nodeblock = blockIdx.x * 64;

    // stage weights (transpose, bf16)
    for (int idx = tid; idx < CHANNELS * CHANNELS; idx += 256) {
        int k = idx >> 5, n = idx & 31;
        W0h[n][k] = f2bf_rne(wbase[idx]);
        W1h[n][k] = f2bf_rne(wbase[CHANNELS * CHANNELS + idx]);
    }
    // stage CSR offsets for this block's 64 nodes (both directions)
    if (tid < 65) {
        int idx = nodeblock + tid;
        offIn[tid]  = (idx <= n_nodes) ? off2[idx] : n_edges;
        int idx2 = n_nodes + idx;
        offOut[tid] = (idx2 < 2 * n_nodes) ? off2[idx2] : 2 * n_edges;
    }
    __syncthreads();

    int c = tid & 31, g = tid >> 5;

    // ---- pipelined pass state ----
    int bi_c, d1_c, bo_c, d2_c, nbl1_c, nbl2_c, node_c;
    float xv_c;
    {
        int local = g;
        node_c = nodeblock + local;
        bi_c = offIn[local];  d1_c = offIn[local + 1] - bi_c;
        bo_c = offOut[local]; d2_c = offOut[local + 1] - bo_c;
        nbl1_c = (c < d1_c) ? nbr[bi_c + c] : 0;
        nbl2_c = (c < d2_c) ? nbr[bo_c + c] : 0;
        xv_c = (node_c < n_nodes)
             ? bfu2f(hi_in[node_c * CHANNELS + c]) + bfu2f(lo[node_c * CHANNELS + c]) : 0.f;
    }

    for (int pass = 0; pass < 8; pass++) {
        // prefetch next pass's index rows + x row (lands during current gathers)
        int bi_n = 0, d1_n = 0, bo_n = 0, d2_n = 0, nbl1_n = 0, nbl2_n = 0, node_n = 0;
        float xv_n = 0.f;
        if (pass < 7) {
            int local = (pass + 1) * 8 + g;
            node_n = nodeblock + local;
            bi_n = offIn[local];  d1_n = offIn[local + 1] - bi_n;
            bo_n = offOut[local]; d2_n = offOut[local + 1] - bo_n;
            nbl1_n = (c < d1_n) ? nbr[bi_n + c] : 0;
            nbl2_n = (c < d2_n) ? nbr[bo_n + c] : 0;
            xv_n = (node_n < n_nodes)
                 ? bfu2f(hi_in[node_n * CHANNELS + c]) + bfu2f(lo[node_n * CHANNELS + c]) : 0.f;
        }

        int local = pass * 8 + g;
        int i = node_c;
        int self = (i < n_nodes) ? i : 0;

        int m1 = d1_c < 32 ? d1_c : 32;
        int m2 = d2_c < 32 ? d2_c : 32;
        int mm = m1 > m2 ? m1 : m2;

        float a1 = 0.f, a2 = 0.f;
        for (int j = 0; j < mm; j += 4) {
            int p0 = __shfl(nbl1_c, (j)     & 31, 32);
            int p1 = __shfl(nbl1_c, (j + 1) & 31, 32);
            int p2 = __shfl(nbl1_c, (j + 2) & 31, 32);
            int p3 = __shfl(nbl1_c, (j + 3) & 31, 32);
            int q0 = __shfl(nbl2_c, (j)     & 31, 32);
            int q1 = __shfl(nbl2_c, (j + 1) & 31, 32);
            int q2 = __shfl(nbl2_c, (j + 2) & 31, 32);
            int q3 = __shfl(nbl2_c, (j + 3) & 31, 32);
            p0 = (j     < m1) ? p0 : self;
            p1 = (j + 1 < m1) ? p1 : self;
            p2 = (j + 2 < m1) ? p2 : self;
            p3 = (j + 3 < m1) ? p3 : self;
            q0 = (j     < m2) ? q0 : self;
            q1 = (j + 1 < m2) ? q1 : self;
            q2 = (j + 2 < m2) ? q2 : self;
            q3 = (j + 3 < m2) ? q3 : self;
            float u0 = bfu2f(hi_in[p0 * CHANNELS + c]);
            float u1 = bfu2f(hi_in[p1 * CHANNELS + c]);
            float u2 = bfu2f(hi_in[p2 * CHANNELS + c]);
            float u3 = bfu2f(hi_in[p3 * CHANNELS + c]);
            float w0 = bfu2f(hi_in[q0 * CHANNELS + c]);
            float w1 = bfu2f(hi_in[q1 * CHANNELS + c]);
            float w2 = bfu2f(hi_in[q2 * CHANNELS + c]);
            float w3 = bfu2f(hi_in[q3 * CHANNELS + c]);
            a1 += (j     < m1) ? u0 : 0.f;
            a1 += (j + 1 < m1) ? u1 : 0.f;
            a1 += (j + 2 < m1) ? u2 : 0.f;
            a1 += (j + 3 < m1) ? u3 : 0.f;
            a2 += (j     < m2) ? w0 : 0.f;
            a2 += (j + 1 < m2) ? w1 : 0.f;
            a2 += (j + 2 < m2) ? w2 : 0.f;
            a2 += (j + 3 < m2) ? w3 : 0.f;
        }
        // rare tails (degree > 32)
        for (int e = bi_c + 32; e < bi_c + d1_c; e++) a1 += bfu2f(hi_in[nbr[e] * CHANNELS + c]);
        for (int e = bo_c + 32; e < bo_c + d2_c; e++) a2 += bfu2f(hi_in[nbr[e] * CHANNELS + c]);

        if (i < n_nodes) {
            float n1 = 1.0f / (1.0f + (float)d1_c);
            float n2 = 1.0f / (1.0f + (float)d2_c);
            a1 = n1 * (xv_c + a1);
            a2 = n2 * (xv_c + a2);
            A1h[local][c] = f2bf_rne(a1);
            A2h[local][c] = f2bf_rne(a2);
        } else {
            A1h[local][c] = 0;
            A2h[local][c] = 0;
        }

        // rotate pipeline
        bi_c = bi_n; d1_c = d1_n; bo_c = bo_n; d2_c = d2_n;
        nbl1_c = nbl1_n; nbl2_c = nbl2_n; xv_c = xv_n; node_c = node_n;
    }
    __syncthreads();

    // ----- MFMA + epilogue -----
    int wv = tid >> 6, lane = tid & 63;
    int m = lane & 15, quad = lane >> 4;
    int row0 = wv * 16;

    short8 a1h = *(const short8*)&A1h[row0 + m][quad * 8];
    short8 a2h = *(const short8*)&A2h[row0 + m][quad * 8];

    float4v dd[4];
#pragma unroll
    for (int h = 0; h < 2; h++) {
        int n0 = h * 16 + m;
        short8 b0h = *(const short8*)&W0h[n0][quad * 8];
        short8 b1h = *(const short8*)&W1h[n0][quad * 8];
        float4v d1 = {0.f, 0.f, 0.f, 0.f};
        d1 = __builtin_amdgcn_mfma_f32_16x16x32_bf16(a1h, b0h, d1, 0, 0, 0);
        float4v d2 = {0.f, 0.f, 0.f, 0.f};
        d2 = __builtin_amdgcn_mfma_f32_16x16x32_bf16(a2h, b1h, d2, 0, 0, 0);
        dd[h * 2] = d1; dd[h * 2 + 1] = d2;
    }

#pragma unroll
    for (int h = 0; h < 2; h++) {
        float4v d1 = dd[h * 2], d2 = dd[h * 2 + 1];
#pragma unroll
        for (int r = 0; r < 4; r++) {
            int local = row0 + quad * 4 + r;
            int node = nodeblock + local;
            if (node < n_nodes) {
                int col = h * 16 + m;
                size_t idx = (size_t)node * CHANNELS + col;
                float base = bfu2f(hi_in[idx]) + bfu2f(lo[idx]);
                float v = base + fmaxf(d1[r], 0.f) + fmaxf(d2[r], 0.f);
                short hn = f2bf_rne(v);
                hi_out[idx] = (unsigned short)hn;
                lo[idx]     = (unsigned short)f2bf_rne(v - bf2f(hn));
            }
        }
    }
}

// ---------------- pooling: run-length accumulate over sorted batch ----------------

#define POOL_CHUNK 2048

__global__ __launch_bounds__(256)
void pool_kernel(const int* __restrict__ batch,
                 const unsigned short* __restrict__ hi,
                 const unsigned short* __restrict__ lo,
                 float* __restrict__ g, int n_nodes) {
    int c = threadIdx.x & 31;
    int r = threadIdx.x >> 5;
    int base = blockIdx.x * POOL_CHUNK;
    float acc = 0.f;
    int cur = -1;
    for (int it = 0; it < POOL_CHUNK / 8; it++) {
        int node = base + it * 8 + r;
        if (node >= n_nodes) break;
        int b = batch[node];
        if (b != cur) {
            if (cur >= 0) atomicAdd(&g[cur * CHANNELS + c], acc);
            acc = 0.f;
            cur = b;
        }
        size_t idx = (size_t)node * CHANNELS + c;
        acc += bfu2f(hi[idx]) + bfu2f(lo[idx]);
    }
    if (cur >= 0) atomicAdd(&g[cur * CHANNELS + c], acc);
}

// ---------------- MLP head: one block per graph ----------------

__global__ __launch_bounds__(256)
void mlp_kernel(const float* __restrict__ g, const float* __restrict__ counts,
                const float* __restrict__ hidden_w, const float* __restrict__ hidden_b,
                const float* __restrict__ out_w, float* __restrict__ out) {
    __shared__ float grow[CHANNELS];
    __shared__ float red[256];
    int graph = blockIdx.x;
    int tid = threadIdx.x;
    if (tid < CHANNELS) grow[tid] = g[graph * CHANNELS + tid] / counts[graph];
    __syncthreads();
    float partial = 0.f;
    for (int q = 0; q < HIDDEN / 256; q++) {
        int j = q * 256 + tid;
        float h = hidden_b[j];
#pragma unroll
        for (int k = 0; k < CHANNELS; k++) h += grow[k] * hidden_w[k * HIDDEN + j];
        partial += fmaxf(h, 0.f) * out_w[j];
    }
    red[tid] = partial;
    __syncthreads();
    for (int s = 128; s > 0; s >>= 1) {
        if (tid < s) red[tid] += red[tid + s];
        __syncthreads();
    }
    if (tid == 0) out[graph] = red[0];
}

// ---------------- launch ----------------

extern "C" void kernel_launch(void* const* d_in, const int* in_sizes, int n_in,
                              void* d_out, int out_size, void* d_ws, size_t ws_size,
                              hipStream_t stream) {
    const int*   nodes    = (const int*)d_in[0];
    const int*   sources  = (const int*)d_in[1];
    const int*   targets  = (const int*)d_in[2];
    const int*   batch    = (const int*)d_in[3];
    const float* emb      = (const float*)d_in[4];
    const float* conv_w   = (const float*)d_in[5];
    const float* hidden_w = (const float*)d_in[6];
    const float* hidden_b = (const float*)d_in[7];
    const float* out_w    = (const float*)d_in[8];
    float* out = (float*)d_out;

    const int n_nodes  = in_sizes[0];
    const int n_edges  = in_sizes[1];
    const int n_graphs = out_size;
    const int n2 = 2 * n_nodes;

    int rsh8 = 0;
    while (((n_nodes - 1) >> rsh8) >= 8) rsh8++;
    int rsh16 = 0;
    while (((n_nodes - 1) >> rsh16) >= 16) rsh16++;

    char* ws = (char*)d_ws;
    unsigned short* hi0 = (unsigned short*)ws; ws += (size_t)n_nodes * CHANNELS * 2;
    unsigned short* hi1 = (unsigned short*)ws; ws += (size_t)n_nodes * CHANNELS * 2;
    unsigned short* lo  = (unsigned short*)ws; ws += (size_t)n_nodes * CHANNELS * 2;
    int*   deg2   = (int*)ws;   ws += (size_t)n2 * 4;
    int*   off2   = (int*)ws;   ws += (size_t)n2 * 4;
    int*   cur2   = (int*)ws;   ws += (size_t)n2 * 4;
    int*   nbr    = (int*)ws;   ws += (size_t)2 * n_edges * 4;
    int*   bsums  = (int*)ws;   ws += 4096;
    float* g      = (float*)ws; ws += (size_t)n_graphs * CHANNELS * 4;
    float* counts = (float*)ws; ws += (size_t)n_graphs * 4;

    hipMemsetAsync(deg2, 0, (size_t)n2 * 4, stream);
    hipMemsetAsync(g, 0, (size_t)n_graphs * CHANNELS * 4, stream);

    int echunks = (n_edges + 2047) / 2048;
    int degB  = echunks * NRANGE;
    int initB = (n_nodes * CHANNELS + 255) / 256;
    int cntB  = (n_graphs + 255) / 256;

    // 1. fused: degrees (range-split) + hi/lo init + graph counts
    pre_kernel<<<degB + initB + cntB, 256, 0, stream>>>(sources, targets, deg2,
                                                        nodes, emb, hi0, lo,
                                                        batch, counts,
                                                        n_nodes, n_edges, n_graphs,
                                                        rsh8, degB, initB);

    // 2. exclusive scan deg2 -> off2
    int nblk = (n2 + 2047) / 2048;
    scan_pass1<<<nblk, 256, 0, stream>>>(deg2, bsums, n2);
    scan_pass2<<<1, 1024, 0, stream>>>(bsums, nblk);
    scan_pass3<<<nblk, 256, 0, stream>>>(deg2, bsums, off2, n2);

    // 3. cursors = offsets copy, then scatter (16 ranges over 2 launches)
    hipMemcpyAsync(cur2, off2, (size_t)n2 * 4, hipMemcpyDeviceToDevice, stream);
    scatter_range_kernel<<<echunks * NRANGE, 256, 0, stream>>>(sources, targets, cur2, nbr,
                                                               n_nodes, n_edges, rsh16, 0);
    scatter_range_kernel<<<echunks * NRANGE, 256, 0, stream>>>(sources, targets, cur2, nbr,
                                                               n_nodes, n_edges, rsh16, 8);

    // 4. layers: hi plane ping-pongs, lo updated in place
    unsigned short* hin = hi0; unsigned short* hout = hi1;
    int lblocks = (n_nodes + 63) / 64;
    for (int l = 0; l < LAYERS; l++) {
        const float* wbase = conv_w + (size_t)l * 2 * CHANNELS * CHANNELS;
        layer_mfma<<<lblocks, 256, 0, stream>>>(off2, nbr, wbase,
                                                hin, hout, lo, n_nodes, n_edges);
        unsigned short* tmp = hin; hin = hout; hout = tmp;
    }
    // after 8 layers result is in hi0 (== hin) + lo

    // 5. pool + head
    int pool_blocks = (n_nodes + POOL_CHUNK - 1) / POOL_CHUNK;
    pool_kernel<<<pool_blocks, 256, 0, stream>>>(batch, hin, lo, g, n_nodes);
    mlp_kernel<<<n_graphs, 256, 0, stream>>>(g, counts, hidden_w, hidden_b, out_w, out);
}